// Round 17
// baseline (187.300 us; speedup 1.0000x reference)
//
#include <hip/hip_runtime.h>

typedef __bf16 bf16x8 __attribute__((ext_vector_type(8)));
typedef float f32x4 __attribute__((ext_vector_type(4)));
typedef float f32x2 __attribute__((ext_vector_type(2)));
typedef short s4 __attribute__((ext_vector_type(4)));
typedef short s8v __attribute__((ext_vector_type(8)));
typedef unsigned short ush;

#define DEV __device__ __forceinline__

// B=8, D_MODEL=512, D_COND=768, N_HEADS=8, dh=64, L=4096, L_COND=256

DEV ush f2bf(float x){
  union { float f; unsigned u; } v; v.f = x;
  unsigned r = v.u + 0x7FFFu + ((v.u >> 16) & 1u);   // RNE
  return (ush)(r >> 16);
}

DEV short bfcast(float x){                  // native f32->bf16, RNE
  union { __bf16 h; short s; } cv; cv.h = (__bf16)x; return cv.s;
}

DEV void gload_lds16(const ush* g, ush* l){
  __builtin_amdgcn_global_load_lds(
      (const __attribute__((address_space(1))) unsigned int*)g,
      (__attribute__((address_space(3))) unsigned int*)l, 16, 0, 0);
}

// ---------------- prep: convert cond + 4 weight matrices to bf16 ----------------
__global__ __launch_bounds__(256) void cvt_kernel(const float* c0,const float* c1,const float* c2,
                                                  const float* c3,const float* c4,
                                                  ush* o0, ush* o1, ush* o2, ush* o3, ush* o4){
  const int N0=1572864, N1=262144, N2=393216, N3=393216, N4=262144;
  const int stride = gridDim.x * blockDim.x;
  for (int i = blockIdx.x*blockDim.x + threadIdx.x; i < N0+N1+N2+N3+N4; i += stride){
    int j = i; const float* s; ush* d;
    if (j < N0){ s=c0; d=o0; }
    else { j-=N0; if (j<N1){s=c1;d=o1;}
      else { j-=N1; if (j<N2){s=c2;d=o2;}
        else { j-=N2; if (j<N3){s=c3;d=o3;} else { j-=N3; s=c4; d=o4; } } } }
    d[j] = f2bf(s[j]);
  }
}

// ---------------- shared GEMM core: C(128x128) = A(rowmajor over K) . B^T(rowmajor over K) ----------------
DEV void gemm_core(const ush* __restrict__ Ag, long long a_row0, int lda,
                   const ush* __restrict__ Bg, long long b_row0, int ldb,
                   int K, ush* As, ush* Bs, f32x4 acc[4][4])
{
  const int t = threadIdx.x;
  const int lane = t & 63;
  const int wid = t >> 6, wr = wid >> 1, wc = wid & 1;
  #pragma unroll
  for (int mt=0;mt<4;mt++)
    #pragma unroll
    for (int nt=0;nt<4;nt++) acc[mt][nt] = f32x4{0.f,0.f,0.f,0.f};

  const int nk = K >> 6;
  for (int kt = 0; kt < nk; ++kt){
    const int k0 = kt << 6;
    #pragma unroll
    for (int r = 0; r < 4; ++r){
      int idx = (r<<8) + t;
      int row = idx >> 3, slot = idx & 7;
      gload_lds16(Ag + (a_row0 + row)*(long long)lda + k0 + ((slot ^ (row&7))<<3), As + idx*8);
    }
    #pragma unroll
    for (int r = 0; r < 4; ++r){
      int idx = (r<<8) + t;
      int row = idx >> 3, slot = idx & 7;
      gload_lds16(Bg + (b_row0 + row)*(long long)ldb + k0 + ((slot ^ (row&7))<<3), Bs + idx*8);
    }
    __syncthreads();
    #pragma unroll
    for (int kk = 0; kk < 2; ++kk){
      bf16x8 af[4], bfv[4];
      #pragma unroll
      for (int mt=0;mt<4;mt++){
        int row = (wr<<6) + (mt<<4) + (lane & 15);
        int byte = (row<<7) + (kk<<6) + ((lane>>4)<<4);
        byte ^= (row & 7) << 4;
        af[mt] = *(const bf16x8*)((const char*)As + byte);
      }
      #pragma unroll
      for (int nt=0;nt<4;nt++){
        int row = (wc<<6) + (nt<<4) + (lane & 15);
        int byte = (row<<7) + (kk<<6) + ((lane>>4)<<4);
        byte ^= (row & 7) << 4;
        bfv[nt] = *(const bf16x8*)((const char*)Bs + byte);
      }
      #pragma unroll
      for (int mt=0;mt<4;mt++)
        #pragma unroll
        for (int nt=0;nt<4;nt++)
          acc[mt][nt] = __builtin_amdgcn_mfma_f32_16x16x32_bf16(af[mt], bfv[nt], acc[mt][nt], 0,0,0);
    }
    __syncthreads();
  }
}

// ---------------- FUSED Q projection v2: A transposed in-REGISTER from fp32 image ----------------
// r16 lesson: LDS stage transpose had 16-way bank conflicts (13.6M cyc) + 6 barriers/K-step.
// v2: thread (lp=t>>2, cg=t&3) loads f32x2 img[(k0+c)*4096 + l0 + 2*lp] for c=cg*16+cc —
// per instruction each 16-lane group reads 128B CONTIGUOUS from one row (4 rows/instr, dense).
// Transpose happens in-register; bf16-convert; write swizzled As chunks (same layout gemm_core
// reads). No stage LDS, 2 barriers/K-step, stage conflicts gone.
__global__ __launch_bounds__(256,2) void qproj_kernel(const float* __restrict__ img, const ush* __restrict__ Wqb,
                                                      ush* __restrict__ Qg){
  __shared__ ush As[8192], Bs[8192];     // 16 KB each
  f32x4 acc[4][4];
  const int t = threadIdx.x;
  const int lane = t & 63;
  const int wid = t >> 6, wr = wid >> 1, wc = wid & 1;
  const int mb = blockIdx.x & 255, nb = blockIdx.x >> 8;   // M=32768 (256 mb), N=512 (4 nb)
  const int bI = mb >> 5;                 // batch
  const int l0 = (mb & 31) << 7;          // l-offset within batch
  const long long b_row0 = (long long)nb * 128;
  const float* imb = img + ((size_t)bI * 512) * 4096 + l0;

  const int lp = t >> 2;                  // 0..63 -> l = 2*lp + r
  const int cg = t & 3;                   // c-group: c = cg*16 + cc

  #pragma unroll
  for (int mt=0;mt<4;mt++)
    #pragma unroll
    for (int nt=0;nt<4;nt++) acc[mt][nt] = f32x4{0.f,0.f,0.f,0.f};

  for (int kt = 0; kt < 8; ++kt){
    const int k0 = kt << 6;
    // B staging (Wq rows) — async, drained by the barrier before MFMA
    #pragma unroll
    for (int r = 0; r < 4; ++r){
      int idx = (r<<8) + t;
      int row = idx >> 3, slot = idx & 7;
      gload_lds16(Wqb + (b_row0 + row)*512LL + k0 + ((slot ^ (row&7))<<3), Bs + idx*8);
    }
    // A: direct global -> reg (transpose via indexing) -> bf16 -> swizzled As
    f32x2 v[16];
    #pragma unroll
    for (int cc = 0; cc < 16; ++cc)
      v[cc] = *(const f32x2*)(imb + (size_t)(k0 + cg*16 + cc)*4096 + (lp<<1));
    #pragma unroll
    for (int r = 0; r < 2; ++r){
      const int l = (lp<<1) + r;
      s8v o0, o1;
      #pragma unroll
      for (int cc = 0; cc < 8; ++cc){ o0[cc] = bfcast(v[cc][r]); o1[cc] = bfcast(v[8+cc][r]); }
      const int ch0 = cg<<1, ch1 = (cg<<1) + 1;
      *(s8v*)(As + l*64 + ((ch0 ^ (l&7))<<3)) = o0;
      *(s8v*)(As + l*64 + ((ch1 ^ (l&7))<<3)) = o1;
    }
    __syncthreads();
    // MFMA over this K-step (identical layout/swizzle to gemm_core)
    #pragma unroll
    for (int kk = 0; kk < 2; ++kk){
      bf16x8 af[4], bfv[4];
      #pragma unroll
      for (int mt=0;mt<4;mt++){
        int row = (wr<<6) + (mt<<4) + (lane & 15);
        int byte = (row<<7) + (kk<<6) + ((lane>>4)<<4);
        byte ^= (row & 7) << 4;
        af[mt] = *(const bf16x8*)((const char*)As + byte);
      }
      #pragma unroll
      for (int nt=0;nt<4;nt++){
        int row = (wc<<6) + (nt<<4) + (lane & 15);
        int byte = (row<<7) + (kk<<6) + ((lane>>4)<<4);
        byte ^= (row & 7) << 4;
        bfv[nt] = *(const bf16x8*)((const char*)Bs + byte);
      }
      #pragma unroll
      for (int mt=0;mt<4;mt++)
        #pragma unroll
        for (int nt=0;nt<4;nt++)
          acc[mt][nt] = __builtin_amdgcn_mfma_f32_16x16x32_bf16(af[mt], bfv[nt], acc[mt][nt], 0,0,0);
    }
    __syncthreads();
  }

  // epilogue: Q written as (b,h,l,dh) bf16, scale 0.125*log2e (exp2-domain softmax)
  #pragma unroll
  for (int mt=0;mt<4;mt++)
    #pragma unroll
    for (int nt=0;nt<4;nt++)
      #pragma unroll
      for (int r=0;r<4;r++){
        int m = mb*128 + (wr<<6) + (mt<<4) + ((lane>>4)<<2) + r;
        int n = (nb<<7) + (wc<<6) + (nt<<4) + (lane&15);
        int bb = m >> 12, l = m & 4095, hh = n >> 6, dh = n & 63;
        Qg[(((size_t)(bb*8 + hh)*4096 + l)<<6) + dh] = f2bf(acc[mt][nt][r] * 0.180336880f);
      }
}

// ---------------- K/V projection: cond . W^T ; K natural (b,j,512), V transposed (b,h,dh,j) ----------------
__global__ __launch_bounds__(256,2) void kvproj_kernel(const ush* __restrict__ cb, const ush* __restrict__ Wkb,
                                                       const ush* __restrict__ Wvb, ush* __restrict__ Kg,
                                                       ush* __restrict__ Vt){
  __shared__ ush As[8192], Bs[8192];
  f32x4 acc[4][4];
  const int which = blockIdx.z;                            // 0=K, 1=V
  const int nb = blockIdx.x & 3, mb = blockIdx.x >> 2;     // M=2048 (16 mb), N=512 (4 nb)
  gemm_core(cb, (long long)mb*128, 768, which ? Wvb : Wkb, (long long)nb*128, 768, 768, As, Bs, acc);
  const int lane = threadIdx.x & 63, wid = threadIdx.x >> 6, wr = wid>>1, wc = wid&1;
  #pragma unroll
  for (int mt=0;mt<4;mt++)
    #pragma unroll
    for (int nt=0;nt<4;nt++)
      #pragma unroll
      for (int r=0;r<4;r++){
        int m = mb*128 + (wr<<6) + (mt<<4) + ((lane>>4)<<2) + r;
        int n = (nb<<7) + (wc<<6) + (nt<<4) + (lane&15);
        int bb = m >> 8, j = m & 255;
        ush val = f2bf(acc[mt][nt][r]);
        if (!which) Kg[(((size_t)(bb*256 + j))<<9) + n] = val;
        else { int hh = n>>6, dh = n&63; Vt[(((size_t)((bb*8+hh)*64 + dh))<<8) + j] = val; }
      }
}

// ---------------- fused attention: r15 body EXACT (locked: 60.5us, spill-free) ----------------
__global__ __launch_bounds__(512,1) void attn_kernel(const ush* __restrict__ Qg, const ush* __restrict__ Kg,
                                                     const ush* __restrict__ Vg, const float* __restrict__ mask,
                                                     ush* __restrict__ Oc){
  extern __shared__ char smem[];
  ush* Ks = (ush*)smem;                  // 32KB: row=key(256) x 128B, swz byte^=(row&7)<<4
  ush* Vs = (ush*)(smem + 32768);        // 32KB: row=dh(64) x 512B,  swz byte^=(row&7)<<4 (per 128B)
  const int t = threadIdx.x, lane = t & 63, wid = t >> 6;
  const int qb = blockIdx.x, h = blockIdx.y, b = blockIdx.z;
  const float L2E = 1.44269504f;

  #pragma unroll
  for (int r = 0; r < 4; ++r){
    int idx = (r<<9) + t;
    int j = idx >> 3, slot = idx & 7;
    gload_lds16(Kg + ((size_t)(b*256 + j))*512 + h*64 + ((slot ^ (j&7))<<3), Ks + idx*8);
  }
  #pragma unroll
  for (int r = 0; r < 4; ++r){
    int idx = (r<<9) + t;
    int dh = idx >> 5, slot = idx & 31;
    gload_lds16(Vg + ((size_t)((b*8 + h)*64 + dh))*256 + ((((slot&7) ^ (dh&7)) | (slot&24))<<3), Vs + idx*8);
  }
  __syncthreads();

  const int l15 = lane & 15, kg = lane >> 4;
  const ush* Qbase = Qg + ((size_t)(b*8 + h)*4096)*64;
  const int q00 = qb*1024 + wid*128;     // 8 waves x 128 q = 1024 q per block, 4 blocks per (b,h)

  #pragma unroll 1
  for (int mp = 0; mp < 4; ++mp){
    const int qA = q00 + mp*32 + l15;    // q-tile A (16 q), this lane's q
    const int qB = qA + 16;              // q-tile B
    bf16x8 qf00 = *(const bf16x8*)(Qbase + (size_t)qA*64 + (kg<<3));
    bf16x8 qf01 = *(const bf16x8*)(Qbase + (size_t)qA*64 + 32 + (kg<<3));
    bf16x8 qf10 = *(const bf16x8*)(Qbase + (size_t)qB*64 + (kg<<3));
    bf16x8 qf11 = *(const bf16x8*)(Qbase + (size_t)qB*64 + 32 + (kg<<3));
    const float* mrowA = mask + ((size_t)b*4096 + qA)*256 + (kg<<2);
    const float* mrowB = mrowA + (16<<8);

    f32x4 oaccA[4], oaccB[4];
    #pragma unroll
    for (int tl=0;tl<4;++tl){ oaccA[tl] = f32x4{0.f,0.f,0.f,0.f}; oaccB[tl] = f32x4{0.f,0.f,0.f,0.f}; }
    float mA = 0.f, mB = 0.f;
    f32x4 svA = f32x4{0.f,0.f,0.f,0.f}, svB = f32x4{0.f,0.f,0.f,0.f};

    #pragma unroll 1
    for (int qt = 0; qt < 4; ++qt){
      f32x4 sA[4], sB[4];
      #pragma unroll
      for (int nt=0;nt<4;++nt){ sA[nt] = f32x4{0.f,0.f,0.f,0.f}; sB[nt] = f32x4{0.f,0.f,0.f,0.f}; }
      #pragma unroll
      for (int nt=0;nt<4;++nt){
        int row = (qt<<6) + (nt<<4) + l15;
        const char* kb = (const char*)Ks + (row<<7);
        int sw = (row&7)<<4;
        bf16x8 kf0 = *(const bf16x8*)(kb + ((kg<<4) ^ sw));
        bf16x8 kf1 = *(const bf16x8*)(kb + (((kg<<4)+64) ^ sw));
        sA[nt] = __builtin_amdgcn_mfma_f32_16x16x32_bf16(kf0, qf00, sA[nt], 0,0,0);
        sA[nt] = __builtin_amdgcn_mfma_f32_16x16x32_bf16(kf1, qf01, sA[nt], 0,0,0);
        sB[nt] = __builtin_amdgcn_mfma_f32_16x16x32_bf16(kf0, qf10, sB[nt], 0,0,0);
        sB[nt] = __builtin_amdgcn_mfma_f32_16x16x32_bf16(kf1, qf11, sB[nt], 0,0,0);
      }

      float mxA = -3.0e38f, mxB = -3.0e38f;
      #pragma unroll
      for (int nt=0;nt<4;++nt){
        float4 va = *(const float4*)(mrowA + (qt<<6) + (nt<<4));
        float4 vb = *(const float4*)(mrowB + (qt<<6) + (nt<<4));
        sA[nt][0] = fmaf(va.x, L2E, sA[nt][0]); sA[nt][1] = fmaf(va.y, L2E, sA[nt][1]);
        sA[nt][2] = fmaf(va.z, L2E, sA[nt][2]); sA[nt][3] = fmaf(va.w, L2E, sA[nt][3]);
        sB[nt][0] = fmaf(vb.x, L2E, sB[nt][0]); sB[nt][1] = fmaf(vb.y, L2E, sB[nt][1]);
        sB[nt][2] = fmaf(vb.z, L2E, sB[nt][2]); sB[nt][3] = fmaf(vb.w, L2E, sB[nt][3]);
        #pragma unroll
        for (int r=0;r<4;++r){ mxA = fmaxf(mxA, sA[nt][r]); mxB = fmaxf(mxB, sB[nt][r]); }
      }
      mxA = fmaxf(mxA, __shfl_xor(mxA, 16, 64));
      mxA = fmaxf(mxA, __shfl_xor(mxA, 32, 64));
      mxB = fmaxf(mxB, __shfl_xor(mxB, 16, 64));
      mxB = fmaxf(mxB, __shfl_xor(mxB, 32, 64));

      if (qt == 0){
        mA = mxA; mB = mxB;
      } else if (!__all(fmaxf(mxA - mA, mxB - mB) <= 8.f)){   // T13 defer-max
        float mnA = fmaxf(mA, mxA), mnB = fmaxf(mB, mxB);
        float aA = exp2f(mA - mnA), aB = exp2f(mB - mnB);
        #pragma unroll
        for (int r=0;r<4;++r){ svA[r] *= aA; svB[r] *= aB; }
        #pragma unroll
        for (int tl=0;tl<4;++tl)
          #pragma unroll
          for (int r=0;r<4;++r){ oaccA[tl][r] *= aA; oaccB[tl][r] *= aB; }
        mA = mnA; mB = mnB;
      }

      #pragma unroll
      for (int nt=0;nt<4;++nt){
        s4 pA, pB;
        #pragma unroll
        for (int r=0;r<4;++r){
          float pa = exp2f(sA[nt][r] - mA);
          float pb = exp2f(sB[nt][r] - mB);
          svA[r] += pa; svB[r] += pb;
          pA[r] = bfcast(pa); pB[r] = bfcast(pb);
        }
        #pragma unroll
        for (int tl=0;tl<4;++tl){
          int dr = (tl<<4) + l15;
          int off = ((qt<<7) + (nt<<5) + (kg<<3)) ^ ((dr&7)<<4);
          s4 vf = *(const s4*)((const char*)Vs + (dr<<9) + off);
          oaccA[tl] = __builtin_amdgcn_mfma_f32_16x16x16bf16_1k(vf, pA, oaccA[tl], 0,0,0);
          oaccB[tl] = __builtin_amdgcn_mfma_f32_16x16x16bf16_1k(vf, pB, oaccB[tl], 0,0,0);
        }
      }
      __builtin_amdgcn_sched_barrier(0);   // no cross-quarter load hoisting (r14: removal => 173MB spill)
    }

    float sAt = (svA[0]+svA[1]) + (svA[2]+svA[3]);
    float sBt = (svB[0]+svB[1]) + (svB[2]+svB[3]);
    sAt += __shfl_xor(sAt, 16, 64); sAt += __shfl_xor(sAt, 32, 64);
    sBt += __shfl_xor(sBt, 16, 64); sBt += __shfl_xor(sBt, 32, 64);
    const float rlA = 1.f / sAt, rlB = 1.f / sBt;
    #pragma unroll
    for (int tl=0;tl<4;++tl){
      s4 ovA, ovB;
      #pragma unroll
      for (int r=0;r<4;++r){ ovA[r] = bfcast(oaccA[tl][r] * rlA); ovB[r] = bfcast(oaccB[tl][r] * rlB); }
      *(s4*)(Oc + (((size_t)b*4096 + qA)<<9) + h*64 + (tl<<4) + (kg<<2)) = ovA;
      *(s4*)(Oc + (((size_t)b*4096 + qB)<<9) + h*64 + (tl<<4) + (kg<<2)) = ovB;
    }
  }
}

// ---------------- output projection: out[b] = Wo . Oc[b]^T + bo  (fp32 out, natural layout) ----------------
__global__ __launch_bounds__(256,2) void oproj_kernel(const ush* __restrict__ Wob, const ush* __restrict__ Oc,
                                                      const float* __restrict__ bo, float* __restrict__ out){
  __shared__ ush As[8192], Bs[8192];
  f32x4 acc[4][4];
  const int bz = blockIdx.z;
  const int mb = blockIdx.x >> 5, nb = blockIdx.x & 31;    // M=512 (4 mb), N=4096 (32 nb)
  gemm_core(Wob, (long long)mb*128, 512, Oc + (size_t)bz*4096*512, (long long)nb*128, 512, 512, As, Bs, acc);
  const int lane = threadIdx.x & 63, wid = threadIdx.x >> 6, wr = wid>>1, wc = wid&1;
  #pragma unroll
  for (int mt=0;mt<4;mt++)
    #pragma unroll
    for (int nt=0;nt<4;nt++){
      #pragma unroll
      for (int r=0;r<4;r++){
        int m = (mb<<7) + (wr<<6) + (mt<<4) + ((lane>>4)<<2) + r;
        int n = (nb<<7) + (wc<<6) + (nt<<4) + (lane&15);
        out[(((size_t)(bz*512 + m))<<12) + n] = acc[mt][nt][r] + bo[m];
      }
    }
}

extern "C" void kernel_launch(void* const* d_in, const int* in_sizes, int n_in,
                              void* d_out, int out_size, void* d_ws, size_t ws_size,
                              hipStream_t stream){
  const float* image = (const float*)d_in[0];
  const float* cond  = (const float*)d_in[1];
  const float* mask  = (const float*)d_in[2];
  const float* Wq    = (const float*)d_in[3];
  const float* Wk    = (const float*)d_in[4];
  const float* Wv    = (const float*)d_in[5];
  const float* Wo    = (const float*)d_in[6];
  const float* bo    = (const float*)d_in[7];
  float* out = (float*)d_out;

  char* ws = (char*)d_ws;
  ush* Oc   = (ush*)(ws);                       // 33,554,432 B  (b,l,512) bf16 attention output
  ush* Qg   = (ush*)(ws + 33554432);            // 33,554,432 B  (b,h,l,dh) bf16
  ush* cndb = (ush*)(ws + 67108864);            //  3,145,728 B
  ush* Kg   = (ush*)(ws + 70254592);            //  2,097,152 B  (b,j,512)
  ush* Vt   = (ush*)(ws + 72351744);            //  2,097,152 B  (b,h,dh,j)
  ush* Wqb  = (ush*)(ws + 74448896);            //    524,288 B
  ush* Wkb  = (ush*)(ws + 74973184);            //    786,432 B
  ush* Wvb  = (ush*)(ws + 75759616);            //    786,432 B
  ush* Wob  = (ush*)(ws + 76546048);            //    524,288 B

  (void)hipFuncSetAttribute((const void*)attn_kernel,
                            hipFuncAttributeMaxDynamicSharedMemorySize, 65536);

  cvt_kernel<<<dim3(1024), 256, 0, stream>>>(cond, Wq, Wk, Wv, Wo, cndb, Wqb, Wkb, Wvb, Wob);
  qproj_kernel<<<dim3(1024), 256, 0, stream>>>(image, Wqb, Qg);
  kvproj_kernel<<<dim3(64,1,2), 256, 0, stream>>>(cndb, Wkb, Wvb, Kg, Vt);
  attn_kernel<<<dim3(4,8,8), 512, 65536, stream>>>(Qg, Kg, Vt, mask, Oc);
  oproj_kernel<<<dim3(128,1,8), 256, 0, stream>>>(Wob, Oc, bo, out);
}

// Round 18
// 156.636 us; speedup vs baseline: 1.1958x; 1.1958x over previous
//
#include <hip/hip_runtime.h>

typedef __bf16 bf16x8 __attribute__((ext_vector_type(8)));
typedef float f32x4 __attribute__((ext_vector_type(4)));
typedef short s4 __attribute__((ext_vector_type(4)));
typedef unsigned short ush;

#define DEV __device__ __forceinline__

// B=8, D_MODEL=512, D_COND=768, N_HEADS=8, dh=64, L=4096, L_COND=256

DEV ush f2bf(float x){
  union { float f; unsigned u; } v; v.f = x;
  unsigned r = v.u + 0x7FFFu + ((v.u >> 16) & 1u);   // RNE
  return (ush)(r >> 16);
}

DEV short bfcast(float x){                  // native f32->bf16, RNE
  union { __bf16 h; short s; } cv; cv.h = (__bf16)x; return cv.s;
}

DEV void gload_lds16(const ush* g, ush* l){
  __builtin_amdgcn_global_load_lds(
      (const __attribute__((address_space(1))) unsigned int*)g,
      (__attribute__((address_space(3))) unsigned int*)l, 16, 0, 0);
}

// ---------------- prep: image transpose-convert (b,512,4096)f32 -> (b*4096,512)bf16 ----------------
// r17/r16 lesson: both qproj-fusion variants regress (bank conflicts / latency-serial codegen).
// The split tc+qproj is the measured optimum — restored from r15.
__global__ __launch_bounds__(256) void tc_kernel(const float* __restrict__ img, ush* __restrict__ xT){
  __shared__ float tile[32][34];          // [c][l], stride 34: float2-aligned writes, 2-way-max reads
  const int b = blockIdx.z;
  const int l0 = blockIdx.x << 5, c0 = blockIdx.y << 5;
  const int rj = threadIdx.x >> 3, cj = threadIdx.x & 7;   // rj 0..31, cj 0..7
  const float* src = img + ((size_t)b*512 + c0 + rj)*4096 + l0 + (cj<<2);
  float4 v = *(const float4*)src;
  *(float2*)&tile[rj][(cj<<2)]     = make_float2(v.x, v.y);
  *(float2*)&tile[rj][(cj<<2) + 2] = make_float2(v.z, v.w);
  __syncthreads();
  s4 o;
  #pragma unroll
  for (int k = 0; k < 4; ++k) o[k] = bfcast(tile[(cj<<2) + k][rj]);
  *(s4*)(xT + ((size_t)b*4096 + l0 + rj)*512 + c0 + (cj<<2)) = o;
}

// ---------------- prep: convert cond + 4 weight matrices to bf16 ----------------
__global__ __launch_bounds__(256) void cvt_kernel(const float* c0,const float* c1,const float* c2,
                                                  const float* c3,const float* c4,
                                                  ush* o0, ush* o1, ush* o2, ush* o3, ush* o4){
  const int N0=1572864, N1=262144, N2=393216, N3=393216, N4=262144;
  const int stride = gridDim.x * blockDim.x;
  for (int i = blockIdx.x*blockDim.x + threadIdx.x; i < N0+N1+N2+N3+N4; i += stride){
    int j = i; const float* s; ush* d;
    if (j < N0){ s=c0; d=o0; }
    else { j-=N0; if (j<N1){s=c1;d=o1;}
      else { j-=N1; if (j<N2){s=c2;d=o2;}
        else { j-=N2; if (j<N3){s=c3;d=o3;} else { j-=N3; s=c4; d=o4; } } } }
    d[j] = f2bf(s[j]);
  }
}

// ---------------- shared GEMM core: C(128x128) = A(rowmajor over K) . B^T(rowmajor over K) ----------------
DEV void gemm_core(const ush* __restrict__ Ag, long long a_row0, int lda,
                   const ush* __restrict__ Bg, long long b_row0, int ldb,
                   int K, ush* As, ush* Bs, f32x4 acc[4][4])
{
  const int t = threadIdx.x;
  const int lane = t & 63;
  const int wid = t >> 6, wr = wid >> 1, wc = wid & 1;
  #pragma unroll
  for (int mt=0;mt<4;mt++)
    #pragma unroll
    for (int nt=0;nt<4;nt++) acc[mt][nt] = f32x4{0.f,0.f,0.f,0.f};

  const int nk = K >> 6;
  for (int kt = 0; kt < nk; ++kt){
    const int k0 = kt << 6;
    #pragma unroll
    for (int r = 0; r < 4; ++r){
      int idx = (r<<8) + t;
      int row = idx >> 3, slot = idx & 7;
      gload_lds16(Ag + (a_row0 + row)*(long long)lda + k0 + ((slot ^ (row&7))<<3), As + idx*8);
    }
    #pragma unroll
    for (int r = 0; r < 4; ++r){
      int idx = (r<<8) + t;
      int row = idx >> 3, slot = idx & 7;
      gload_lds16(Bg + (b_row0 + row)*(long long)ldb + k0 + ((slot ^ (row&7))<<3), Bs + idx*8);
    }
    __syncthreads();
    #pragma unroll
    for (int kk = 0; kk < 2; ++kk){
      bf16x8 af[4], bfv[4];
      #pragma unroll
      for (int mt=0;mt<4;mt++){
        int row = (wr<<6) + (mt<<4) + (lane & 15);
        int byte = (row<<7) + (kk<<6) + ((lane>>4)<<4);
        byte ^= (row & 7) << 4;
        af[mt] = *(const bf16x8*)((const char*)As + byte);
      }
      #pragma unroll
      for (int nt=0;nt<4;nt++){
        int row = (wc<<6) + (nt<<4) + (lane & 15);
        int byte = (row<<7) + (kk<<6) + ((lane>>4)<<4);
        byte ^= (row & 7) << 4;
        bfv[nt] = *(const bf16x8*)((const char*)Bs + byte);
      }
      #pragma unroll
      for (int mt=0;mt<4;mt++)
        #pragma unroll
        for (int nt=0;nt<4;nt++)
          acc[mt][nt] = __builtin_amdgcn_mfma_f32_16x16x32_bf16(af[mt], bfv[nt], acc[mt][nt], 0,0,0);
    }
    __syncthreads();
  }
}

// ---------------- Q projection: Q = (xT . Wq^T) * 0.125 * log2(e), written as (b,h,l,dh) bf16 ----
__global__ __launch_bounds__(256,2) void qproj_kernel(const ush* __restrict__ xT, const ush* __restrict__ Wqb,
                                                      ush* __restrict__ Qg){
  __shared__ ush As[8192], Bs[8192];
  f32x4 acc[4][4];
  const int mb = blockIdx.x & 255, nb = blockIdx.x >> 8;   // M=32768 (256 mb), N=512 (4 nb)
  gemm_core(xT, (long long)mb*128, 512, Wqb, (long long)nb*128, 512, 512, As, Bs, acc);
  const int lane = threadIdx.x & 63, wid = threadIdx.x >> 6, wr = wid>>1, wc = wid&1;
  #pragma unroll
  for (int mt=0;mt<4;mt++)
    #pragma unroll
    for (int nt=0;nt<4;nt++)
      #pragma unroll
      for (int r=0;r<4;r++){
        int m = mb*128 + (wr<<6) + (mt<<4) + ((lane>>4)<<2) + r;
        int n = (nb<<7) + (wc<<6) + (nt<<4) + (lane&15);
        int bb = m >> 12, l = m & 4095, hh = n >> 6, dh = n & 63;
        Qg[(((size_t)(bb*8 + hh)*4096 + l)<<6) + dh] = f2bf(acc[mt][nt][r] * 0.180336880f);
      }
}

// ---------------- K/V projection: cond . W^T ; K natural (b,j,512), V transposed (b,h,dh,j) ----------------
__global__ __launch_bounds__(256,2) void kvproj_kernel(const ush* __restrict__ cb, const ush* __restrict__ Wkb,
                                                       const ush* __restrict__ Wvb, ush* __restrict__ Kg,
                                                       ush* __restrict__ Vt){
  __shared__ ush As[8192], Bs[8192];
  f32x4 acc[4][4];
  const int which = blockIdx.z;                            // 0=K, 1=V
  const int nb = blockIdx.x & 3, mb = blockIdx.x >> 2;     // M=2048 (16 mb), N=512 (4 nb)
  gemm_core(cb, (long long)mb*128, 768, which ? Wvb : Wkb, (long long)nb*128, 768, 768, As, Bs, acc);
  const int lane = threadIdx.x & 63, wid = threadIdx.x >> 6, wr = wid>>1, wc = wid&1;
  #pragma unroll
  for (int mt=0;mt<4;mt++)
    #pragma unroll
    for (int nt=0;nt<4;nt++)
      #pragma unroll
      for (int r=0;r<4;r++){
        int m = mb*128 + (wr<<6) + (mt<<4) + ((lane>>4)<<2) + r;
        int n = (nb<<7) + (wc<<6) + (nt<<4) + (lane&15);
        int bb = m >> 8, j = m & 255;
        ush val = f2bf(acc[mt][nt][r]);
        if (!which) Kg[(((size_t)(bb*256 + j))<<9) + n] = val;
        else { int hh = n>>6, dh = n&63; Vt[(((size_t)((bb*8+hh)*64 + dh))<<8) + j] = val; }
      }
}

// ---------------- fused attention: r15 body + EARLY mask prefetch inside each qt window ----------
// Change vs r15 (single change, falsifier-guarded): the 8 mask float4 loads move from AFTER the
// QK MFMA loop to BEFORE it — their ~900cyc HBM latency now overlaps the QK phase within the
// same fence window (the qt-end sched_barrier previously forced a serial stall per qt).
// Liveness +32 regs (va/vb[4]), peak ~115 < 128 wall. Falsifier: WRITE > 33.5MB => spill, revert.
__global__ __launch_bounds__(512,1) void attn_kernel(const ush* __restrict__ Qg, const ush* __restrict__ Kg,
                                                     const ush* __restrict__ Vg, const float* __restrict__ mask,
                                                     ush* __restrict__ Oc){
  extern __shared__ char smem[];
  ush* Ks = (ush*)smem;                  // 32KB: row=key(256) x 128B, swz byte^=(row&7)<<4
  ush* Vs = (ush*)(smem + 32768);        // 32KB: row=dh(64) x 512B,  swz byte^=(row&7)<<4 (per 128B)
  const int t = threadIdx.x, lane = t & 63, wid = t >> 6;
  const int qb = blockIdx.x, h = blockIdx.y, b = blockIdx.z;
  const float L2E = 1.44269504f;

  #pragma unroll
  for (int r = 0; r < 4; ++r){
    int idx = (r<<9) + t;
    int j = idx >> 3, slot = idx & 7;
    gload_lds16(Kg + ((size_t)(b*256 + j))*512 + h*64 + ((slot ^ (j&7))<<3), Ks + idx*8);
  }
  #pragma unroll
  for (int r = 0; r < 4; ++r){
    int idx = (r<<9) + t;
    int dh = idx >> 5, slot = idx & 31;
    gload_lds16(Vg + ((size_t)((b*8 + h)*64 + dh))*256 + ((((slot&7) ^ (dh&7)) | (slot&24))<<3), Vs + idx*8);
  }
  __syncthreads();

  const int l15 = lane & 15, kg = lane >> 4;
  const ush* Qbase = Qg + ((size_t)(b*8 + h)*4096)*64;
  const int q00 = qb*1024 + wid*128;     // 8 waves x 128 q = 1024 q per block, 4 blocks per (b,h)

  #pragma unroll 1
  for (int mp = 0; mp < 4; ++mp){
    const int qA = q00 + mp*32 + l15;    // q-tile A (16 q), this lane's q
    const int qB = qA + 16;              // q-tile B
    bf16x8 qf00 = *(const bf16x8*)(Qbase + (size_t)qA*64 + (kg<<3));
    bf16x8 qf01 = *(const bf16x8*)(Qbase + (size_t)qA*64 + 32 + (kg<<3));
    bf16x8 qf10 = *(const bf16x8*)(Qbase + (size_t)qB*64 + (kg<<3));
    bf16x8 qf11 = *(const bf16x8*)(Qbase + (size_t)qB*64 + 32 + (kg<<3));
    const float* mrowA = mask + ((size_t)b*4096 + qA)*256 + (kg<<2);
    const float* mrowB = mrowA + (16<<8);

    f32x4 oaccA[4], oaccB[4];
    #pragma unroll
    for (int tl=0;tl<4;++tl){ oaccA[tl] = f32x4{0.f,0.f,0.f,0.f}; oaccB[tl] = f32x4{0.f,0.f,0.f,0.f}; }
    float mA = 0.f, mB = 0.f;
    f32x4 svA = f32x4{0.f,0.f,0.f,0.f}, svB = f32x4{0.f,0.f,0.f,0.f};

    #pragma unroll 1
    for (int qt = 0; qt < 4; ++qt){
      // ---- EARLY mask prefetch: issue before QK so HBM latency hides under the MFMA phase
      float4 va[4], vb[4];
      #pragma unroll
      for (int nt=0;nt<4;++nt){
        va[nt] = *(const float4*)(mrowA + (qt<<6) + (nt<<4));
        vb[nt] = *(const float4*)(mrowB + (qt<<6) + (nt<<4));
      }

      // ---- QK^T over 64 keys (log2 domain): each kf feeds BOTH q-tiles
      f32x4 sA[4], sB[4];
      #pragma unroll
      for (int nt=0;nt<4;++nt){ sA[nt] = f32x4{0.f,0.f,0.f,0.f}; sB[nt] = f32x4{0.f,0.f,0.f,0.f}; }
      #pragma unroll
      for (int nt=0;nt<4;++nt){
        int row = (qt<<6) + (nt<<4) + l15;
        const char* kb = (const char*)Ks + (row<<7);
        int sw = (row&7)<<4;
        bf16x8 kf0 = *(const bf16x8*)(kb + ((kg<<4) ^ sw));
        bf16x8 kf1 = *(const bf16x8*)(kb + (((kg<<4)+64) ^ sw));
        sA[nt] = __builtin_amdgcn_mfma_f32_16x16x32_bf16(kf0, qf00, sA[nt], 0,0,0);
        sA[nt] = __builtin_amdgcn_mfma_f32_16x16x32_bf16(kf1, qf01, sA[nt], 0,0,0);
        sB[nt] = __builtin_amdgcn_mfma_f32_16x16x32_bf16(kf0, qf10, sB[nt], 0,0,0);
        sB[nt] = __builtin_amdgcn_mfma_f32_16x16x32_bf16(kf1, qf11, sB[nt], 0,0,0);
      }

      // ---- + mask*log2e (FMA, values already in regs), local max for this quarter
      float mxA = -3.0e38f, mxB = -3.0e38f;
      #pragma unroll
      for (int nt=0;nt<4;++nt){
        sA[nt][0] = fmaf(va[nt].x, L2E, sA[nt][0]); sA[nt][1] = fmaf(va[nt].y, L2E, sA[nt][1]);
        sA[nt][2] = fmaf(va[nt].z, L2E, sA[nt][2]); sA[nt][3] = fmaf(va[nt].w, L2E, sA[nt][3]);
        sB[nt][0] = fmaf(vb[nt].x, L2E, sB[nt][0]); sB[nt][1] = fmaf(vb[nt].y, L2E, sB[nt][1]);
        sB[nt][2] = fmaf(vb[nt].z, L2E, sB[nt][2]); sB[nt][3] = fmaf(vb[nt].w, L2E, sB[nt][3]);
        #pragma unroll
        for (int r=0;r<4;++r){ mxA = fmaxf(mxA, sA[nt][r]); mxB = fmaxf(mxB, sB[nt][r]); }
      }
      mxA = fmaxf(mxA, __shfl_xor(mxA, 16, 64));
      mxA = fmaxf(mxA, __shfl_xor(mxA, 32, 64));
      mxB = fmaxf(mxB, __shfl_xor(mxB, 16, 64));
      mxB = fmaxf(mxB, __shfl_xor(mxB, 32, 64));

      if (qt == 0){
        mA = mxA; mB = mxB;
      } else if (!__all(fmaxf(mxA - mA, mxB - mB) <= 8.f)){   // T13 defer-max
        float mnA = fmaxf(mA, mxA), mnB = fmaxf(mB, mxB);
        float aA = exp2f(mA - mnA), aB = exp2f(mB - mnB);
        #pragma unroll
        for (int r=0;r<4;++r){ svA[r] *= aA; svB[r] *= aB; }
        #pragma unroll
        for (int tl=0;tl<4;++tl)
          #pragma unroll
          for (int r=0;r<4;++r){ oaccA[tl][r] *= aA; oaccB[tl][r] *= aB; }
        mA = mnA; mB = mnB;
      }

      // ---- exp2 -> bf16 -> PV, fused per nt (sA/sB[nt] die right here; no extra arrays)
      #pragma unroll
      for (int nt=0;nt<4;++nt){
        s4 pA, pB;
        #pragma unroll
        for (int r=0;r<4;++r){
          float pa = exp2f(sA[nt][r] - mA);
          float pb = exp2f(sB[nt][r] - mB);
          svA[r] += pa; svB[r] += pb;
          pA[r] = bfcast(pa); pB[r] = bfcast(pb);
        }
        #pragma unroll
        for (int tl=0;tl<4;++tl){
          int dr = (tl<<4) + l15;
          int off = ((qt<<7) + (nt<<5) + (kg<<3)) ^ ((dr&7)<<4);
          s4 vf = *(const s4*)((const char*)Vs + (dr<<9) + off);
          oaccA[tl] = __builtin_amdgcn_mfma_f32_16x16x16bf16_1k(vf, pA, oaccA[tl], 0,0,0);
          oaccB[tl] = __builtin_amdgcn_mfma_f32_16x16x16bf16_1k(vf, pB, oaccB[tl], 0,0,0);
        }
      }
      __builtin_amdgcn_sched_barrier(0);   // no cross-quarter load hoisting (r14: removal => 173MB spill)
    }

    // ---- final 1/sum (cross-kg) and store 4 consecutive dh as one b64, both q-tiles
    float sAt = (svA[0]+svA[1]) + (svA[2]+svA[3]);
    float sBt = (svB[0]+svB[1]) + (svB[2]+svB[3]);
    sAt += __shfl_xor(sAt, 16, 64); sAt += __shfl_xor(sAt, 32, 64);
    sBt += __shfl_xor(sBt, 16, 64); sBt += __shfl_xor(sBt, 32, 64);
    const float rlA = 1.f / sAt, rlB = 1.f / sBt;
    #pragma unroll
    for (int tl=0;tl<4;++tl){
      s4 ovA, ovB;
      #pragma unroll
      for (int r=0;r<4;++r){ ovA[r] = bfcast(oaccA[tl][r] * rlA); ovB[r] = bfcast(oaccB[tl][r] * rlB); }
      *(s4*)(Oc + (((size_t)b*4096 + qA)<<9) + h*64 + (tl<<4) + (kg<<2)) = ovA;
      *(s4*)(Oc + (((size_t)b*4096 + qB)<<9) + h*64 + (tl<<4) + (kg<<2)) = ovB;
    }
  }
}

// ---------------- output projection: out[b] = Wo . Oc[b]^T + bo  (fp32 out, natural layout) ----------------
__global__ __launch_bounds__(256,2) void oproj_kernel(const ush* __restrict__ Wob, const ush* __restrict__ Oc,
                                                      const float* __restrict__ bo, float* __restrict__ out){
  __shared__ ush As[8192], Bs[8192];
  f32x4 acc[4][4];
  const int bz = blockIdx.z;
  const int mb = blockIdx.x >> 5, nb = blockIdx.x & 31;    // M=512 (4 mb), N=4096 (32 nb)
  gemm_core(Wob, (long long)mb*128, 512, Oc + (size_t)bz*4096*512, (long long)nb*128, 512, 512, As, Bs, acc);
  const int lane = threadIdx.x & 63, wid = threadIdx.x >> 6, wr = wid>>1, wc = wid&1;
  #pragma unroll
  for (int mt=0;mt<4;mt++)
    #pragma unroll
    for (int nt=0;nt<4;nt++){
      #pragma unroll
      for (int r=0;r<4;r++){
        int m = (mb<<7) + (wr<<6) + (mt<<4) + ((lane>>4)<<2) + r;
        int n = (nb<<7) + (wc<<6) + (nt<<4) + (lane&15);
        out[(((size_t)(bz*512 + m))<<12) + n] = acc[mt][nt][r] + bo[m];
      }
    }
}

extern "C" void kernel_launch(void* const* d_in, const int* in_sizes, int n_in,
                              void* d_out, int out_size, void* d_ws, size_t ws_size,
                              hipStream_t stream){
  const float* image = (const float*)d_in[0];
  const float* cond  = (const float*)d_in[1];
  const float* mask  = (const float*)d_in[2];
  const float* Wq    = (const float*)d_in[3];
  const float* Wk    = (const float*)d_in[4];
  const float* Wv    = (const float*)d_in[5];
  const float* Wo    = (const float*)d_in[6];
  const float* bo    = (const float*)d_in[7];
  float* out = (float*)d_out;

  char* ws = (char*)d_ws;
  ush* xT   = (ush*)(ws);                       // 33,554,432 B  (b*4096, 512) bf16
  ush* Oc   = xT;                               // aliased: xT dead after qproj
  ush* Qg   = (ush*)(ws + 33554432);            // 33,554,432 B  (b,h,l,dh) bf16
  ush* cndb = (ush*)(ws + 67108864);            //  3,145,728 B
  ush* Kg   = (ush*)(ws + 70254592);            //  2,097,152 B  (b,j,512)
  ush* Vt   = (ush*)(ws + 72351744);            //  2,097,152 B  (b,h,dh,j)
  ush* Wqb  = (ush*)(ws + 74448896);            //    524,288 B
  ush* Wkb  = (ush*)(ws + 74973184);            //    786,432 B
  ush* Wvb  = (ush*)(ws + 75759616);            //    786,432 B
  ush* Wob  = (ush*)(ws + 76546048);            //    524,288 B

  (void)hipFuncSetAttribute((const void*)attn_kernel,
                            hipFuncAttributeMaxDynamicSharedMemorySize, 65536);

  tc_kernel<<<dim3(128,16,8), 256, 0, stream>>>(image, xT);
  cvt_kernel<<<dim3(1024), 256, 0, stream>>>(cond, Wq, Wk, Wv, Wo, cndb, Wqb, Wkb, Wvb, Wob);
  qproj_kernel<<<dim3(1024), 256, 0, stream>>>(xT, Wqb, Qg);
  kvproj_kernel<<<dim3(64,1,2), 256, 0, stream>>>(cndb, Wkb, Wvb, Kg, Vt);
  attn_kernel<<<dim3(4,8,8), 512, 65536, stream>>>(Qg, Kg, Vt, mask, Oc);
  oproj_kernel<<<dim3(128,1,8), 256, 0, stream>>>(Wob, Oc, bo, out);
}